// Round 3
// baseline (732.060 us; speedup 1.0000x reference)
//
#include <hip/hip_runtime.h>

#define LRELU(v) ((v) > 0.f ? (v) : 0.2f * (v))

// ---------------- GEMMs (unchanged) ----------------

__global__ void gemm_k128_n256(const float* __restrict__ A, const float* __restrict__ B,
                               float* __restrict__ C, int M) {
    __shared__ float As[8][128];
    const int row0 = blockIdx.x * 8;
    if (row0 >= M) return;
    const int tid = threadIdx.x;
    ((float4*)&As[0][0])[tid] = ((const float4*)(A + (size_t)row0 * 128))[tid];
    __syncthreads();
    float acc[8] = {0.f, 0.f, 0.f, 0.f, 0.f, 0.f, 0.f, 0.f};
    const float* __restrict__ Bc = B + tid;
#pragma unroll 4
    for (int k = 0; k < 128; ++k) {
        float wv = Bc[(size_t)k * 256];
#pragma unroll
        for (int r = 0; r < 8; ++r) acc[r] += As[r][k] * wv;
    }
#pragma unroll
    for (int r = 0; r < 8; ++r) C[(size_t)(row0 + r) * 256 + tid] = acc[r];
}

__global__ void gemm_k256_n64(const float* __restrict__ A, const float* __restrict__ B,
                              float* __restrict__ C, int M) {
    __shared__ float As[16][256];
    const int row0 = blockIdx.x * 16;
    if (row0 >= M) return;
    const int tid = threadIdx.x;
    {
        const float4* src = (const float4*)(A + (size_t)row0 * 256);
        float4* dstl = (float4*)&As[0][0];
#pragma unroll
        for (int i = 0; i < 4; ++i) dstl[tid + i * 256] = src[tid + i * 256];
    }
    __syncthreads();
    const int col = tid & 63, g = tid >> 6;
    float acc[4] = {0.f, 0.f, 0.f, 0.f};
    const float* __restrict__ Bc = B + col;
#pragma unroll 4
    for (int k = 0; k < 256; ++k) {
        float wv = Bc[(size_t)k * 64];
#pragma unroll
        for (int r = 0; r < 4; ++r) acc[r] += As[g * 4 + r][k] * wv;
    }
#pragma unroll
    for (int r = 0; r < 4; ++r) C[(size_t)(row0 + g * 4 + r) * 64 + col] = acc[r];
}

// ---------------- attention dot products ----------------

__global__ void attn_h4(const float* __restrict__ h, const float* __restrict__ asrc,
                        const float* __restrict__ adst, float* __restrict__ os,
                        float* __restrict__ od, int N) {
    const int n = blockIdx.x;
    if (n >= N) return;
    const int t = threadIdx.x;
    float v = h[(size_t)n * 256 + t];
    float s = v * asrc[t];
    float d = v * adst[t];
#pragma unroll
    for (int m = 1; m < 64; m <<= 1) { s += __shfl_xor(s, m); d += __shfl_xor(d, m); }
    if ((t & 63) == 0) { os[n * 4 + (t >> 6)] = s; od[n * 4 + (t >> 6)] = d; }
}

__global__ void attn_h1(const float* __restrict__ h, const float* __restrict__ asrc,
                        const float* __restrict__ adst, float* __restrict__ os,
                        float* __restrict__ od, int N) {
    const int n = blockIdx.x * 4 + (threadIdx.x >> 6);
    if (n >= N) return;
    const int c = threadIdx.x & 63;
    float v = h[(size_t)n * 64 + c];
    float s = v * asrc[c];
    float d = v * adst[c];
#pragma unroll
    for (int m = 1; m < 64; m <<= 1) { s += __shfl_xor(s, m); d += __shfl_xor(d, m); }
    if (c == 0) { os[n] = s; od[n] = d; }
}

// ---------------- CSR build ----------------

__global__ void hist_k(const int* __restrict__ ei, int E, int* __restrict__ cnt) {
    int e = blockIdx.x * blockDim.x + threadIdx.x;
    if (e < E) atomicAdd(&cnt[ei[E + e]], 1);
}

// per-block exclusive scan; bsum[b] = block total
__global__ void scan1_k(const int* __restrict__ cnt, int* __restrict__ off,
                        int* __restrict__ bsum, int N) {
    __shared__ int tmp[256];
    const int i = blockIdx.x * 256 + threadIdx.x;
    int v = (i < N) ? cnt[i] : 0;
    tmp[threadIdx.x] = v;
    __syncthreads();
#pragma unroll
    for (int d = 1; d < 256; d <<= 1) {
        int t = (threadIdx.x >= d) ? tmp[threadIdx.x - d] : 0;
        __syncthreads();
        tmp[threadIdx.x] += t;
        __syncthreads();
    }
    if (i < N) off[i] = tmp[threadIdx.x] - v;
    if (threadIdx.x == 255) bsum[blockIdx.x] = tmp[255];
}

// add prefix of bsum[0..b-1]; each wave reduces the block totals itself
__global__ void scan23_k(int* __restrict__ off, const int* __restrict__ bsum, int N) {
    const int b = blockIdx.x;
    int pre = 0;
    for (int i = (threadIdx.x & 63); i < b; i += 64) pre += bsum[i];
#pragma unroll
    for (int m = 1; m < 64; m <<= 1) pre += __shfl_xor(pre, m);
    int i = b * 256 + threadIdx.x;
    if (i < N) off[i] += pre;
}

__global__ void fill_k(const int* __restrict__ ei, int E, int* __restrict__ off,
                       int* __restrict__ csr) {
    int e = blockIdx.x * blockDim.x + threadIdx.x;
    if (e >= E) return;
    int s = ei[e], d = ei[E + e];
    csr[atomicAdd(&off[d], 1)] = s;
}

// ---------------- softmax denominator (edge-parallel, L2-resident atomics) ----------------
// den[d,h] = sum over incoming edges (incl. self-loop) of exp(lrelu(as[s,h]+ad[d,h]))

template <int H>
__global__ void eden_k(const int* __restrict__ ei, int E, int N,
                       const float* __restrict__ as, const float* __restrict__ ad,
                       float* __restrict__ den) {
    int e = blockIdx.x * blockDim.x + threadIdx.x;
    if (e >= E + N) return;
    int s, d;
    if (e < E) { s = ei[e]; d = ei[E + e]; } else { s = d = e - E; }
#pragma unroll
    for (int h = 0; h < H; ++h) {
        float v = LRELU(as[s * H + h] + ad[d * H + h]);
        atomicAdd(&den[d * H + h], __expf(v));
    }
}

// ---------------- pull aggregation (no softmax state in the loop) ----------------

// layer 1: one WAVE per node; lane loads float4 -> full 1KB row per instr-wave.
// lane l: head = l>>4, channels (l&15)*4 .. +3
__global__ __launch_bounds__(256) void pull1_k(
        const int* __restrict__ endp, const int* __restrict__ cnt,
        const int* __restrict__ csr, const float* __restrict__ h,
        const float* __restrict__ as, const float* __restrict__ ad,
        const float* __restrict__ den, const float* __restrict__ bias,
        float* __restrict__ agg, int N) {
    const int n = blockIdx.x * 4 + (threadIdx.x >> 6);
    if (n >= N) return;
    const int lane = threadIdx.x & 63;
    const int hh = lane >> 4;
    const float adv = ad[n * 4 + hh];
    const float rden = 1.f / den[n * 4 + hh];
    const int end = endp[n];
    const int start = end - cnt[n];
    float4 acc = {0.f, 0.f, 0.f, 0.f};
    int s_next = (start < end) ? csr[start] : 0;
    for (int i = start; i < end; ++i) {
        const int s = s_next;
        if (i + 1 < end) s_next = csr[i + 1];
        const float p = __expf(LRELU(as[s * 4 + hh] + adv));
        const float4 hv = *(const float4*)(h + (size_t)s * 256 + lane * 4);
        acc.x += p * hv.x; acc.y += p * hv.y; acc.z += p * hv.z; acc.w += p * hv.w;
    }
    {   // self-loop
        const float p = __expf(LRELU(as[n * 4 + hh] + adv));
        const float4 hv = *(const float4*)(h + (size_t)n * 256 + lane * 4);
        acc.x += p * hv.x; acc.y += p * hv.y; acc.z += p * hv.z; acc.w += p * hv.w;
    }
    const float4 bv = *(const float4*)(bias + lane * 4);
    float4 o;
    o.x = fmaxf(acc.x * rden + bv.x, 0.f);
    o.y = fmaxf(acc.y * rden + bv.y, 0.f);
    o.z = fmaxf(acc.z * rden + bv.z, 0.f);
    o.w = fmaxf(acc.w * rden + bv.w, 0.f);
    *(float4*)(agg + (size_t)n * 256 + lane * 4) = o;
}

// layer 2: one wave per node, 4 edges per iteration (16 lanes x float4 per edge);
// fused bias + L2 normalize, writes final output rows
__global__ __launch_bounds__(256) void pull2_k(
        const int* __restrict__ endp, const int* __restrict__ cnt,
        const int* __restrict__ csr, const float* __restrict__ h,
        const float* __restrict__ as, const float* __restrict__ ad,
        const float* __restrict__ den, const float* __restrict__ bias,
        float* __restrict__ out, int N) {
    const int n = blockIdx.x * 4 + (threadIdx.x >> 6);
    if (n >= N) return;
    const int lane = threadIdx.x & 63;
    const int g = lane >> 4;          // edge sub-group 0..3
    const int q = lane & 15;          // channel quad
    const float adv = ad[n];
    const float rden = 1.f / den[n];
    const int end = endp[n];
    const int start = end - cnt[n];
    float4 acc = {0.f, 0.f, 0.f, 0.f};
    for (int base = start; base < end; base += 4) {
        const int idx = base + g;
        const bool valid = idx < end;
        const int s = valid ? csr[idx] : n;
        float p = __expf(LRELU(as[s] + adv));
        if (!valid) p = 0.f;
        const float4 hv = *(const float4*)(h + (size_t)s * 64 + q * 4);
        acc.x += p * hv.x; acc.y += p * hv.y; acc.z += p * hv.z; acc.w += p * hv.w;
    }
    if (g == 0) {   // self-loop counted once
        const float p = __expf(LRELU(as[n] + adv));
        const float4 hv = *(const float4*)(h + (size_t)n * 64 + q * 4);
        acc.x += p * hv.x; acc.y += p * hv.y; acc.z += p * hv.z; acc.w += p * hv.w;
    }
#pragma unroll
    for (int m = 16; m < 64; m <<= 1) {   // sum the 4 edge groups
        acc.x += __shfl_xor(acc.x, m); acc.y += __shfl_xor(acc.y, m);
        acc.z += __shfl_xor(acc.z, m); acc.w += __shfl_xor(acc.w, m);
    }
    const float4 bv = *(const float4*)(bias + q * 4);
    float4 v;
    v.x = acc.x * rden + bv.x; v.y = acc.y * rden + bv.y;
    v.z = acc.z * rden + bv.z; v.w = acc.w * rden + bv.w;
    float ss = v.x * v.x + v.y * v.y + v.z * v.z + v.w * v.w;
#pragma unroll
    for (int m = 1; m < 16; m <<= 1) ss += __shfl_xor(ss, m);
    const float rn = 1.f / fmaxf(sqrtf(ss), 1e-12f);
    if (g == 0) {
        float4 o; o.x = v.x * rn; o.y = v.y * rn; o.z = v.z * rn; o.w = v.w * rn;
        *(float4*)(out + (size_t)n * 64 + q * 4) = o;
    }
}

// ---------------- launch ----------------

extern "C" void kernel_launch(void* const* d_in, const int* in_sizes, int n_in,
                              void* d_out, int out_size, void* d_ws, size_t ws_size,
                              hipStream_t stream) {
    const float* x   = (const float*)d_in[0];
    const int*   ei1 = (const int*)d_in[1];
    const int*   ei2 = (const int*)d_in[2];
    const float* W1  = (const float*)d_in[3];
    const float* as1 = (const float*)d_in[4];
    const float* ad1 = (const float*)d_in[5];
    const float* b1  = (const float*)d_in[6];
    const float* W2  = (const float*)d_in[7];
    const float* as2 = (const float*)d_in[8];
    const float* ad2 = (const float*)d_in[9];
    const float* b2  = (const float*)d_in[10];

    const int N  = in_sizes[0] / 128;
    const int E1 = in_sizes[1] / 2;
    const int E2 = in_sizes[2] / 2;
    const int Emax = E1 > E2 ? E1 : E2;

    // ws: the two big node-feature buffers (102.4 MB)
    float* h1   = (float*)d_ws;                 // N*256; layer-2 h reuses
    float* agg1 = h1 + (size_t)N * 256;         // N*256; final-out temp reuses
    float* h2   = h1;
    float* otmp = agg1;

    // d_out doubles as scratch until the final copy
    int*   csr  = (int*)d_out;                  // Emax
    int*   cnt  = csr + Emax;                   // N     (cnt|den contiguous for one memset)
    float* den  = (float*)(cnt + N);            // N*4 (layer1) / N (layer2)
    int*   off  = (int*)(den + (size_t)N * 4);  // N
    int*   bsum = off + N;                      // 256
    float* s1   = (float*)(bsum + 256);         // N*4
    float* d1v  = s1 + (size_t)N * 4;           // N*4
    float* s2   = d1v + (size_t)N * 4;          // N
    float* d2v  = s2 + N;                       // N

    const int nb = (N + 255) / 256;

    // ---- layer 1 ----
    gemm_k128_n256<<<(N + 7) / 8, 256, 0, stream>>>(x, W1, h1, N);
    attn_h4<<<N, 256, 0, stream>>>(h1, as1, ad1, s1, d1v, N);

    hipMemsetAsync(cnt, 0, (size_t)N * 5 * sizeof(int), stream);   // cnt + den
    hist_k<<<(E1 + 255) / 256, 256, 0, stream>>>(ei1, E1, cnt);
    scan1_k<<<nb, 256, 0, stream>>>(cnt, off, bsum, N);
    scan23_k<<<nb, 256, 0, stream>>>(off, bsum, N);
    fill_k<<<(E1 + 255) / 256, 256, 0, stream>>>(ei1, E1, off, csr);
    eden_k<4><<<(E1 + N + 255) / 256, 256, 0, stream>>>(ei1, E1, N, s1, d1v, den);

    pull1_k<<<(N + 3) / 4, 256, 0, stream>>>(off, cnt, csr, h1, s1, d1v, den, b1, agg1, N);

    // ---- layer 2 ----
    gemm_k256_n64<<<(N + 15) / 16, 256, 0, stream>>>(agg1, W2, h2, N);
    attn_h1<<<(N + 3) / 4, 256, 0, stream>>>(h2, as2, ad2, s2, d2v, N);

    hipMemsetAsync(cnt, 0, (size_t)N * 2 * sizeof(int), stream);   // cnt + den[0:N]
    hist_k<<<(E2 + 255) / 256, 256, 0, stream>>>(ei2, E2, cnt);
    scan1_k<<<nb, 256, 0, stream>>>(cnt, off, bsum, N);
    scan23_k<<<nb, 256, 0, stream>>>(off, bsum, N);
    fill_k<<<(E2 + 255) / 256, 256, 0, stream>>>(ei2, E2, off, csr);
    eden_k<1><<<(E2 + N + 255) / 256, 256, 0, stream>>>(ei2, E2, N, s2, d2v, den);

    pull2_k<<<(N + 3) / 4, 256, 0, stream>>>(off, cnt, csr, h2, s2, d2v, den, b2, otmp, N);

    // ---- publish ----
    hipMemcpyAsync(d_out, otmp, (size_t)N * 64 * sizeof(float),
                   hipMemcpyDeviceToDevice, stream);
}

// Round 4
// 503.952 us; speedup vs baseline: 1.4526x; 1.4526x over previous
//
#include <hip/hip_runtime.h>

#define LRELU(v) ((v) > 0.f ? (v) : 0.2f * (v))

// ---------------- GEMMs (unchanged) ----------------

__global__ void gemm_k128_n256(const float* __restrict__ A, const float* __restrict__ B,
                               float* __restrict__ C, int M) {
    __shared__ float As[8][128];
    const int row0 = blockIdx.x * 8;
    if (row0 >= M) return;
    const int tid = threadIdx.x;
    ((float4*)&As[0][0])[tid] = ((const float4*)(A + (size_t)row0 * 128))[tid];
    __syncthreads();
    float acc[8] = {0.f, 0.f, 0.f, 0.f, 0.f, 0.f, 0.f, 0.f};
    const float* __restrict__ Bc = B + tid;
#pragma unroll 4
    for (int k = 0; k < 128; ++k) {
        float wv = Bc[(size_t)k * 256];
#pragma unroll
        for (int r = 0; r < 8; ++r) acc[r] += As[r][k] * wv;
    }
#pragma unroll
    for (int r = 0; r < 8; ++r) C[(size_t)(row0 + r) * 256 + tid] = acc[r];
}

__global__ void gemm_k256_n64(const float* __restrict__ A, const float* __restrict__ B,
                              float* __restrict__ C, int M) {
    __shared__ float As[16][256];
    const int row0 = blockIdx.x * 16;
    if (row0 >= M) return;
    const int tid = threadIdx.x;
    {
        const float4* src = (const float4*)(A + (size_t)row0 * 256);
        float4* dstl = (float4*)&As[0][0];
#pragma unroll
        for (int i = 0; i < 4; ++i) dstl[tid + i * 256] = src[tid + i * 256];
    }
    __syncthreads();
    const int col = tid & 63, g = tid >> 6;
    float acc[4] = {0.f, 0.f, 0.f, 0.f};
    const float* __restrict__ Bc = B + col;
#pragma unroll 4
    for (int k = 0; k < 256; ++k) {
        float wv = Bc[(size_t)k * 64];
#pragma unroll
        for (int r = 0; r < 4; ++r) acc[r] += As[g * 4 + r][k] * wv;
    }
#pragma unroll
    for (int r = 0; r < 4; ++r) C[(size_t)(row0 + g * 4 + r) * 64 + col] = acc[r];
}

// ---------------- attention dot products ----------------

__global__ void attn_h4(const float* __restrict__ h, const float* __restrict__ asrc,
                        const float* __restrict__ adst, float* __restrict__ os,
                        float* __restrict__ od, int N) {
    const int n = blockIdx.x;
    if (n >= N) return;
    const int t = threadIdx.x;
    float v = h[(size_t)n * 256 + t];
    float s = v * asrc[t];
    float d = v * adst[t];
#pragma unroll
    for (int m = 1; m < 64; m <<= 1) { s += __shfl_xor(s, m); d += __shfl_xor(d, m); }
    if ((t & 63) == 0) { os[n * 4 + (t >> 6)] = s; od[n * 4 + (t >> 6)] = d; }
}

__global__ void attn_h1(const float* __restrict__ h, const float* __restrict__ asrc,
                        const float* __restrict__ adst, float* __restrict__ os,
                        float* __restrict__ od, int N) {
    const int n = blockIdx.x * 4 + (threadIdx.x >> 6);
    if (n >= N) return;
    const int c = threadIdx.x & 63;
    float v = h[(size_t)n * 64 + c];
    float s = v * asrc[c];
    float d = v * adst[c];
#pragma unroll
    for (int m = 1; m < 64; m <<= 1) { s += __shfl_xor(s, m); d += __shfl_xor(d, m); }
    if (c == 0) { os[n] = s; od[n] = d; }
}

// ---------------- CSR build ----------------

__global__ void hist_k(const int* __restrict__ ei, int E, int* __restrict__ cnt) {
    int e = blockIdx.x * blockDim.x + threadIdx.x;
    if (e < E) atomicAdd(&cnt[ei[E + e]], 1);
}

__global__ void scan1_k(const int* __restrict__ cnt, int* __restrict__ off,
                        int* __restrict__ bsum, int N) {
    __shared__ int tmp[256];
    const int i = blockIdx.x * 256 + threadIdx.x;
    int v = (i < N) ? cnt[i] : 0;
    tmp[threadIdx.x] = v;
    __syncthreads();
#pragma unroll
    for (int d = 1; d < 256; d <<= 1) {
        int t = (threadIdx.x >= d) ? tmp[threadIdx.x - d] : 0;
        __syncthreads();
        tmp[threadIdx.x] += t;
        __syncthreads();
    }
    if (i < N) off[i] = tmp[threadIdx.x] - v;
    if (threadIdx.x == 255) bsum[blockIdx.x] = tmp[255];
}

__global__ void scan23_k(int* __restrict__ off, const int* __restrict__ bsum, int N) {
    const int b = blockIdx.x;
    int pre = 0;
    for (int i = (threadIdx.x & 63); i < b; i += 64) pre += bsum[i];
#pragma unroll
    for (int m = 1; m < 64; m <<= 1) pre += __shfl_xor(pre, m);
    int i = b * 256 + threadIdx.x;
    if (i < N) off[i] += pre;
}

__global__ void fill_k(const int* __restrict__ ei, int E, int* __restrict__ off,
                       int* __restrict__ csr) {
    int e = blockIdx.x * blockDim.x + threadIdx.x;
    if (e >= E) return;
    int s = ei[e], d = ei[E + e];
    csr[atomicAdd(&off[d], 1)] = s;
}

// ---------------- pull aggregation (den accumulated in-loop, no atomics) ----------------

// layer 1: one WAVE per node; lane l: head = l>>4, channel quad = l&15.
// den needs no reduction: all 16 lanes of a head group compute identical den.
__global__ __launch_bounds__(256) void pull1_k(
        const int* __restrict__ endp, const int* __restrict__ cnt,
        const int* __restrict__ csr, const float* __restrict__ h,
        const float* __restrict__ as, const float* __restrict__ ad,
        const float* __restrict__ bias, float* __restrict__ agg, int N) {
    const int n = blockIdx.x * 4 + (threadIdx.x >> 6);
    if (n >= N) return;
    const int lane = threadIdx.x & 63;
    const int hh = lane >> 4;
    const float adv = ad[n * 4 + hh];
    const int end = endp[n];
    const int start = end - cnt[n];
    float4 acc = {0.f, 0.f, 0.f, 0.f};
    float den = 0.f;
    int s_next = (start < end) ? csr[start] : 0;
    for (int i = start; i < end; ++i) {
        const int s = s_next;
        if (i + 1 < end) s_next = csr[i + 1];
        const float p = __expf(LRELU(as[s * 4 + hh] + adv));
        const float4 hv = *(const float4*)(h + (size_t)s * 256 + lane * 4);
        den += p;
        acc.x += p * hv.x; acc.y += p * hv.y; acc.z += p * hv.z; acc.w += p * hv.w;
    }
    {   // self-loop
        const float p = __expf(LRELU(as[n * 4 + hh] + adv));
        const float4 hv = *(const float4*)(h + (size_t)n * 256 + lane * 4);
        den += p;
        acc.x += p * hv.x; acc.y += p * hv.y; acc.z += p * hv.z; acc.w += p * hv.w;
    }
    const float rden = 1.f / den;
    const float4 bv = *(const float4*)(bias + lane * 4);
    float4 o;
    o.x = fmaxf(acc.x * rden + bv.x, 0.f);
    o.y = fmaxf(acc.y * rden + bv.y, 0.f);
    o.z = fmaxf(acc.z * rden + bv.z, 0.f);
    o.w = fmaxf(acc.w * rden + bv.w, 0.f);
    *(float4*)(agg + (size_t)n * 256 + lane * 4) = o;
}

// layer 2: one wave per node, 4 edges/iter (16 lanes x float4 each);
// den reduced across edge groups together with acc; fused bias + L2 norm.
__global__ __launch_bounds__(256) void pull2_k(
        const int* __restrict__ endp, const int* __restrict__ cnt,
        const int* __restrict__ csr, const float* __restrict__ h,
        const float* __restrict__ as, const float* __restrict__ ad,
        const float* __restrict__ bias, float* __restrict__ out, int N) {
    const int n = blockIdx.x * 4 + (threadIdx.x >> 6);
    if (n >= N) return;
    const int lane = threadIdx.x & 63;
    const int g = lane >> 4;          // edge sub-group 0..3
    const int q = lane & 15;          // channel quad
    const float adv = ad[n];
    const int end = endp[n];
    const int start = end - cnt[n];
    float4 acc = {0.f, 0.f, 0.f, 0.f};
    float den = 0.f;
    for (int base = start; base < end; base += 4) {
        const int idx = base + g;
        const bool valid = idx < end;
        const int s = valid ? csr[idx] : n;
        float p = __expf(LRELU(as[s] + adv));
        if (!valid) p = 0.f;
        const float4 hv = *(const float4*)(h + (size_t)s * 64 + q * 4);
        den += p;
        acc.x += p * hv.x; acc.y += p * hv.y; acc.z += p * hv.z; acc.w += p * hv.w;
    }
    if (g == 0) {   // self-loop counted once
        const float p = __expf(LRELU(as[n] + adv));
        const float4 hv = *(const float4*)(h + (size_t)n * 64 + q * 4);
        den += p;
        acc.x += p * hv.x; acc.y += p * hv.y; acc.z += p * hv.z; acc.w += p * hv.w;
    }
#pragma unroll
    for (int m = 16; m < 64; m <<= 1) {   // sum the 4 edge groups
        acc.x += __shfl_xor(acc.x, m); acc.y += __shfl_xor(acc.y, m);
        acc.z += __shfl_xor(acc.z, m); acc.w += __shfl_xor(acc.w, m);
        den   += __shfl_xor(den, m);
    }
    const float rden = 1.f / den;
    const float4 bv = *(const float4*)(bias + q * 4);
    float4 v;
    v.x = acc.x * rden + bv.x; v.y = acc.y * rden + bv.y;
    v.z = acc.z * rden + bv.z; v.w = acc.w * rden + bv.w;
    float ss = v.x * v.x + v.y * v.y + v.z * v.z + v.w * v.w;
#pragma unroll
    for (int m = 1; m < 16; m <<= 1) ss += __shfl_xor(ss, m);
    const float rn = 1.f / fmaxf(sqrtf(ss), 1e-12f);
    if (g == 0) {
        float4 o; o.x = v.x * rn; o.y = v.y * rn; o.z = v.z * rn; o.w = v.w * rn;
        *(float4*)(out + (size_t)n * 64 + q * 4) = o;
    }
}

// ---------------- launch ----------------

extern "C" void kernel_launch(void* const* d_in, const int* in_sizes, int n_in,
                              void* d_out, int out_size, void* d_ws, size_t ws_size,
                              hipStream_t stream) {
    const float* x   = (const float*)d_in[0];
    const int*   ei1 = (const int*)d_in[1];
    const int*   ei2 = (const int*)d_in[2];
    const float* W1  = (const float*)d_in[3];
    const float* as1 = (const float*)d_in[4];
    const float* ad1 = (const float*)d_in[5];
    const float* b1  = (const float*)d_in[6];
    const float* W2  = (const float*)d_in[7];
    const float* as2 = (const float*)d_in[8];
    const float* ad2 = (const float*)d_in[9];
    const float* b2  = (const float*)d_in[10];

    const int N  = in_sizes[0] / 128;
    const int E1 = in_sizes[1] / 2;
    const int E2 = in_sizes[2] / 2;
    const int Emax = E1 > E2 ? E1 : E2;

    // ws: the two big node-feature buffers (102.4 MB)
    float* h1   = (float*)d_ws;                 // N*256; layer-2 h reuses
    float* agg1 = h1 + (size_t)N * 256;         // N*256; final-out temp reuses
    float* h2   = h1;
    float* otmp = agg1;

    // d_out doubles as scratch until the final copy
    int*   csr  = (int*)d_out;                  // Emax
    int*   cnt  = csr + Emax;                   // N
    int*   off  = cnt + N;                      // N (mutated into end-pointers by fill_k)
    int*   bsum = off + N;                      // 256
    float* s1   = (float*)(bsum + 256);         // N*4
    float* d1v  = s1 + (size_t)N * 4;           // N*4
    float* s2   = d1v + (size_t)N * 4;          // N
    float* d2v  = s2 + N;                       // N

    const int nb = (N + 255) / 256;

    // ---- layer 1 ----
    gemm_k128_n256<<<(N + 7) / 8, 256, 0, stream>>>(x, W1, h1, N);
    attn_h4<<<N, 256, 0, stream>>>(h1, as1, ad1, s1, d1v, N);

    hipMemsetAsync(cnt, 0, (size_t)N * sizeof(int), stream);
    hist_k<<<(E1 + 255) / 256, 256, 0, stream>>>(ei1, E1, cnt);
    scan1_k<<<nb, 256, 0, stream>>>(cnt, off, bsum, N);
    scan23_k<<<nb, 256, 0, stream>>>(off, bsum, N);
    fill_k<<<(E1 + 255) / 256, 256, 0, stream>>>(ei1, E1, off, csr);

    pull1_k<<<(N + 3) / 4, 256, 0, stream>>>(off, cnt, csr, h1, s1, d1v, b1, agg1, N);

    // ---- layer 2 ----
    gemm_k256_n64<<<(N + 15) / 16, 256, 0, stream>>>(agg1, W2, h2, N);
    attn_h1<<<(N + 3) / 4, 256, 0, stream>>>(h2, as2, ad2, s2, d2v, N);

    hipMemsetAsync(cnt, 0, (size_t)N * sizeof(int), stream);
    hist_k<<<(E2 + 255) / 256, 256, 0, stream>>>(ei2, E2, cnt);
    scan1_k<<<nb, 256, 0, stream>>>(cnt, off, bsum, N);
    scan23_k<<<nb, 256, 0, stream>>>(off, bsum, N);
    fill_k<<<(E2 + 255) / 256, 256, 0, stream>>>(ei2, E2, off, csr);

    pull2_k<<<(N + 3) / 4, 256, 0, stream>>>(off, cnt, csr, h2, s2, d2v, b2, otmp, N);

    // ---- publish ----
    hipMemcpyAsync(d_out, otmp, (size_t)N * 64 * sizeof(float),
                   hipMemcpyDeviceToDevice, stream);
}

// Round 5
// 357.194 us; speedup vs baseline: 2.0495x; 1.4109x over previous
//
#include <hip/hip_runtime.h>

#define LRELU(v) ((v) > 0.f ? (v) : 0.2f * (v))

__device__ __forceinline__ ushort f2bf(float x) {
    union { float f; unsigned u; } v; v.f = x;
    return (ushort)((v.u + 0x7FFF + ((v.u >> 16) & 1)) >> 16);   // RNE
}
__device__ __forceinline__ float bf2f(ushort b) {
    union { float f; unsigned u; } v; v.u = ((unsigned)b) << 16;
    return v.f;
}

// ---------------- GEMM1 + fused attn dots + bf16 h out ----------------
// C[M,256] = A[M,128] @ B[128,256]; 8 rows/block; wave w == head w.

__global__ __launch_bounds__(256) void gemm1_fused(
        const float* __restrict__ A, const float* __restrict__ B,
        const float* __restrict__ asrc, const float* __restrict__ adst,
        ushort* __restrict__ hb, float* __restrict__ os, float* __restrict__ od,
        int M) {
    __shared__ float As[8][128];
    const int row0 = blockIdx.x * 8;
    if (row0 >= M) return;
    const int tid = threadIdx.x;
    ((float4*)&As[0][0])[tid] = ((const float4*)(A + (size_t)row0 * 128))[tid];
    __syncthreads();
    float acc[8] = {0.f, 0.f, 0.f, 0.f, 0.f, 0.f, 0.f, 0.f};
    const float* __restrict__ Bc = B + tid;
#pragma unroll 4
    for (int k = 0; k < 128; ++k) {
        float wv = Bc[(size_t)k * 256];
#pragma unroll
        for (int r = 0; r < 8; ++r) acc[r] += As[r][k] * wv;
    }
    const float aw_s = asrc[tid], aw_d = adst[tid];
    const int hh = tid >> 6, lane = tid & 63;
#pragma unroll
    for (int r = 0; r < 8; ++r) {
        hb[(size_t)(row0 + r) * 256 + tid] = f2bf(acc[r]);
        float s = acc[r] * aw_s, d = acc[r] * aw_d;
#pragma unroll
        for (int m = 1; m < 64; m <<= 1) { s += __shfl_xor(s, m); d += __shfl_xor(d, m); }
        if (lane == 0) { os[(row0 + r) * 4 + hh] = s; od[(row0 + r) * 4 + hh] = d; }
    }
}

// ---------------- GEMM2 + fused attn dots + bf16 h out ----------------
// C[M,64] = A[M,256] @ B[256,64]; 16 rows/block; wave g owns rows g*4..+3.

__global__ __launch_bounds__(256) void gemm2_fused(
        const float* __restrict__ A, const float* __restrict__ B,
        const float* __restrict__ asrc, const float* __restrict__ adst,
        ushort* __restrict__ hb, float* __restrict__ os, float* __restrict__ od,
        int M) {
    __shared__ float As[16][256];
    const int row0 = blockIdx.x * 16;
    if (row0 >= M) return;
    const int tid = threadIdx.x;
    {
        const float4* src = (const float4*)(A + (size_t)row0 * 256);
        float4* dstl = (float4*)&As[0][0];
#pragma unroll
        for (int i = 0; i < 4; ++i) dstl[tid + i * 256] = src[tid + i * 256];
    }
    __syncthreads();
    const int col = tid & 63, g = tid >> 6;
    float acc[4] = {0.f, 0.f, 0.f, 0.f};
    const float* __restrict__ Bc = B + col;
#pragma unroll 4
    for (int k = 0; k < 256; ++k) {
        float wv = Bc[(size_t)k * 64];
#pragma unroll
        for (int r = 0; r < 4; ++r) acc[r] += As[g * 4 + r][k] * wv;
    }
    const float aw_s = asrc[col], aw_d = adst[col];
#pragma unroll
    for (int r = 0; r < 4; ++r) {
        const int row = row0 + g * 4 + r;
        hb[(size_t)row * 64 + col] = f2bf(acc[r]);
        float s = acc[r] * aw_s, d = acc[r] * aw_d;
#pragma unroll
        for (int m = 1; m < 64; m <<= 1) { s += __shfl_xor(s, m); d += __shfl_xor(d, m); }
        if (col == 0) { os[row] = s; od[row] = d; }
    }
}

// ---------------- CSR build: rank -> scan -> place (one atomic pass) ----------------

__global__ void rank_k(const int* __restrict__ ei, int E,
                       int* __restrict__ cnt, int* __restrict__ rnk) {
    int e = blockIdx.x * blockDim.x + threadIdx.x;
    if (e < E) rnk[e] = atomicAdd(&cnt[ei[E + e]], 1);
}

__global__ void scan1_k(const int* __restrict__ cnt, int* __restrict__ off,
                        int* __restrict__ bsum, int N) {
    __shared__ int tmp[256];
    const int i = blockIdx.x * 256 + threadIdx.x;
    int v = (i < N) ? cnt[i] : 0;
    tmp[threadIdx.x] = v;
    __syncthreads();
#pragma unroll
    for (int d = 1; d < 256; d <<= 1) {
        int t = (threadIdx.x >= d) ? tmp[threadIdx.x - d] : 0;
        __syncthreads();
        tmp[threadIdx.x] += t;
        __syncthreads();
    }
    if (i < N) off[i] = tmp[threadIdx.x] - v;
    if (threadIdx.x == 255) bsum[blockIdx.x] = tmp[255];
}

__global__ void scan23_k(int* __restrict__ off, const int* __restrict__ bsum, int N) {
    const int b = blockIdx.x;
    int pre = 0;
    for (int i = (threadIdx.x & 63); i < b; i += 64) pre += bsum[i];
#pragma unroll
    for (int m = 1; m < 64; m <<= 1) pre += __shfl_xor(pre, m);
    int i = b * 256 + threadIdx.x;
    if (i < N) off[i] += pre;
}

__global__ void place_k(const int* __restrict__ ei, int E, const int* __restrict__ off,
                        const int* __restrict__ rnk, int* __restrict__ csr) {
    int e = blockIdx.x * blockDim.x + threadIdx.x;
    if (e >= E) return;
    csr[off[ei[E + e]] + rnk[e]] = ei[e];
}

// ---------------- pull aggregation (bf16 gathers) ----------------

// layer 1: one wave per node; lane l: head = l>>4, channel quad = l&15 (8B bf16 load)
__global__ __launch_bounds__(256) void pull1_k(
        const int* __restrict__ off, const int* __restrict__ cnt,
        const int* __restrict__ csr, const ushort* __restrict__ hb,
        const float* __restrict__ as, const float* __restrict__ ad,
        const float* __restrict__ bias, float* __restrict__ agg, int N) {
    const int n = blockIdx.x * 4 + (threadIdx.x >> 6);
    if (n >= N) return;
    const int lane = threadIdx.x & 63;
    const int hh = lane >> 4;
    const float adv = ad[n * 4 + hh];
    const int start = off[n];
    const int end = start + cnt[n];
    float4 acc = {0.f, 0.f, 0.f, 0.f};
    float den = 0.f;
    int s_next = (start < end) ? csr[start] : 0;
    for (int i = start; i < end; ++i) {
        const int s = s_next;
        if (i + 1 < end) s_next = csr[i + 1];
        const float p = __expf(LRELU(as[s * 4 + hh] + adv));
        const ushort4 hv = *(const ushort4*)(hb + (size_t)s * 256 + lane * 4);
        den += p;
        acc.x += p * bf2f(hv.x); acc.y += p * bf2f(hv.y);
        acc.z += p * bf2f(hv.z); acc.w += p * bf2f(hv.w);
    }
    {   // self-loop
        const float p = __expf(LRELU(as[n * 4 + hh] + adv));
        const ushort4 hv = *(const ushort4*)(hb + (size_t)n * 256 + lane * 4);
        den += p;
        acc.x += p * bf2f(hv.x); acc.y += p * bf2f(hv.y);
        acc.z += p * bf2f(hv.z); acc.w += p * bf2f(hv.w);
    }
    const float rden = 1.f / den;
    const float4 bv = *(const float4*)(bias + lane * 4);
    float4 o;
    o.x = fmaxf(acc.x * rden + bv.x, 0.f);
    o.y = fmaxf(acc.y * rden + bv.y, 0.f);
    o.z = fmaxf(acc.z * rden + bv.z, 0.f);
    o.w = fmaxf(acc.w * rden + bv.w, 0.f);
    *(float4*)(agg + (size_t)n * 256 + lane * 4) = o;
}

// layer 2: one wave per node, 4 edges/iter (16 lanes x 8B bf16 each);
// fused bias + L2 normalize; writes final output directly.
__global__ __launch_bounds__(256) void pull2_k(
        const int* __restrict__ off, const int* __restrict__ cnt,
        const int* __restrict__ csr, const ushort* __restrict__ hb,
        const float* __restrict__ as, const float* __restrict__ ad,
        const float* __restrict__ bias, float* __restrict__ out, int N) {
    const int n = blockIdx.x * 4 + (threadIdx.x >> 6);
    if (n >= N) return;
    const int lane = threadIdx.x & 63;
    const int g = lane >> 4;          // edge sub-group 0..3
    const int q = lane & 15;          // channel quad
    const float adv = ad[n];
    const int start = off[n];
    const int end = start + cnt[n];
    float4 acc = {0.f, 0.f, 0.f, 0.f};
    float den = 0.f;
    for (int base = start; base < end; base += 4) {
        const int idx = base + g;
        const bool valid = idx < end;
        const int s = valid ? csr[idx] : n;
        float p = __expf(LRELU(as[s] + adv));
        if (!valid) p = 0.f;
        const ushort4 hv = *(const ushort4*)(hb + (size_t)s * 64 + q * 4);
        den += p;
        acc.x += p * bf2f(hv.x); acc.y += p * bf2f(hv.y);
        acc.z += p * bf2f(hv.z); acc.w += p * bf2f(hv.w);
    }
    if (g == 0) {   // self-loop counted once
        const float p = __expf(LRELU(as[n] + adv));
        const ushort4 hv = *(const ushort4*)(hb + (size_t)n * 64 + q * 4);
        den += p;
        acc.x += p * bf2f(hv.x); acc.y += p * bf2f(hv.y);
        acc.z += p * bf2f(hv.z); acc.w += p * bf2f(hv.w);
    }
#pragma unroll
    for (int m = 16; m < 64; m <<= 1) {
        acc.x += __shfl_xor(acc.x, m); acc.y += __shfl_xor(acc.y, m);
        acc.z += __shfl_xor(acc.z, m); acc.w += __shfl_xor(acc.w, m);
        den   += __shfl_xor(den, m);
    }
    const float rden = 1.f / den;
    const float4 bv = *(const float4*)(bias + q * 4);
    float4 v;
    v.x = acc.x * rden + bv.x; v.y = acc.y * rden + bv.y;
    v.z = acc.z * rden + bv.z; v.w = acc.w * rden + bv.w;
    float ss = v.x * v.x + v.y * v.y + v.z * v.z + v.w * v.w;
#pragma unroll
    for (int m = 1; m < 16; m <<= 1) ss += __shfl_xor(ss, m);
    const float rn = 1.f / fmaxf(sqrtf(ss), 1e-12f);
    if (g == 0) {
        float4 o; o.x = v.x * rn; o.y = v.y * rn; o.z = v.z * rn; o.w = v.w * rn;
        *(float4*)(out + (size_t)n * 64 + q * 4) = o;
    }
}

// ---------------- launch ----------------

extern "C" void kernel_launch(void* const* d_in, const int* in_sizes, int n_in,
                              void* d_out, int out_size, void* d_ws, size_t ws_size,
                              hipStream_t stream) {
    const float* x   = (const float*)d_in[0];
    const int*   ei1 = (const int*)d_in[1];
    const int*   ei2 = (const int*)d_in[2];
    const float* W1  = (const float*)d_in[3];
    const float* as1 = (const float*)d_in[4];
    const float* ad1 = (const float*)d_in[5];
    const float* b1  = (const float*)d_in[6];
    const float* W2  = (const float*)d_in[7];
    const float* as2 = (const float*)d_in[8];
    const float* ad2 = (const float*)d_in[9];
    const float* b2  = (const float*)d_in[10];

    const int N  = in_sizes[0] / 128;
    const int E1 = in_sizes[1] / 2;
    const int E2 = in_sizes[2] / 2;
    const int Emax = E1 > E2 ? E1 : E2;

    // all scratch in d_ws (~92 MB; 106.4 MB proven available in round 0)
    ushort* h1b  = (ushort*)d_ws;                       // N*256 bf16 (25.6 MB)
    float*  agg1 = (float*)(h1b + (size_t)N * 256);     // N*256 f32  (51.2 MB)
    ushort* h2b  = (ushort*)(agg1 + (size_t)N * 256);   // N*64 bf16  (6.4 MB)
    int*    csr  = (int*)(h2b + (size_t)N * 64);        // Emax
    int*    rnk  = csr + Emax;                          // Emax
    int*    cnt  = rnk + Emax;                          // N
    int*    off  = cnt + N;                             // N
    int*    bsum = off + N;                             // 256
    float*  s1   = (float*)(bsum + 256);                // N*4
    float*  d1v  = s1 + (size_t)N * 4;                  // N*4
    float*  s2   = d1v + (size_t)N * 4;                 // N
    float*  d2v  = s2 + N;                              // N
    float*  out  = (float*)d_out;

    const int nb = (N + 255) / 256;

    // ---- layer 1 ----
    gemm1_fused<<<(N + 7) / 8, 256, 0, stream>>>(x, W1, as1, ad1, h1b, s1, d1v, N);

    hipMemsetAsync(cnt, 0, (size_t)N * sizeof(int), stream);
    rank_k<<<(E1 + 255) / 256, 256, 0, stream>>>(ei1, E1, cnt, rnk);
    scan1_k<<<nb, 256, 0, stream>>>(cnt, off, bsum, N);
    scan23_k<<<nb, 256, 0, stream>>>(off, bsum, N);
    place_k<<<(E1 + 255) / 256, 256, 0, stream>>>(ei1, E1, off, rnk, csr);

    pull1_k<<<(N + 3) / 4, 256, 0, stream>>>(off, cnt, csr, h1b, s1, d1v, b1, agg1, N);

    // ---- layer 2 ----
    gemm2_fused<<<(N + 15) / 16, 256, 0, stream>>>(agg1, W2, as2, ad2, h2b, s2, d2v, N);

    hipMemsetAsync(cnt, 0, (size_t)N * sizeof(int), stream);
    rank_k<<<(E2 + 255) / 256, 256, 0, stream>>>(ei2, E2, cnt, rnk);
    scan1_k<<<nb, 256, 0, stream>>>(cnt, off, bsum, N);
    scan23_k<<<nb, 256, 0, stream>>>(off, bsum, N);
    place_k<<<(E2 + 255) / 256, 256, 0, stream>>>(ei2, E2, off, rnk, csr);

    pull2_k<<<(N + 3) / 4, 256, 0, stream>>>(off, cnt, csr, h2b, s2, d2v, b2, out, N);
}

// Round 6
// 301.606 us; speedup vs baseline: 2.4272x; 1.1843x over previous
//
#include <hip/hip_runtime.h>

#define LRELU(v) ((v) > 0.f ? (v) : 0.2f * (v))

typedef __attribute__((ext_vector_type(8))) short bf16x8;
typedef __attribute__((ext_vector_type(4))) float f32x4;

__device__ __forceinline__ ushort f2bf(float x) {
    union { float f; unsigned u; } v; v.f = x;
    return (ushort)((v.u + 0x7FFF + ((v.u >> 16) & 1)) >> 16);   // RNE
}
__device__ __forceinline__ float bf2f(ushort b) {
    union { float f; unsigned u; } v; v.u = ((unsigned)b) << 16;
    return v.f;
}

// ---------------- prep casts ----------------

__global__ void cast4_k(const float* __restrict__ src, ushort* __restrict__ dst, int n4) {
    int i = blockIdx.x * blockDim.x + threadIdx.x;
    if (i >= n4) return;
    float4 v = ((const float4*)src)[i];
    ushort4 o = { f2bf(v.x), f2bf(v.y), f2bf(v.z), f2bf(v.w) };
    ((ushort4*)dst)[i] = o;
}

// src[K][N] f32 -> dst[N][K] bf16
__global__ void tcast_k(const float* __restrict__ src, ushort* __restrict__ dst, int K, int N) {
    int i = blockIdx.x * blockDim.x + threadIdx.x;
    if (i >= K * N) return;
    int k = i / N, c = i - k * N;
    dst[c * K + k] = f2bf(src[i]);
}

// ---------------- MFMA GEMM1: h1[M,256] = xb[M,128] @ W1, + attn dots ----------------
// 256 thr = 4 waves; wave owns 16 rows x 256 cols (16 col-tiles), K=128 (4 k-steps).
// frag layouts (16x16x32 bf16): A lane l -> row l&15, k = (l>>4)*8..+7
//                               B lane l -> col l&15, k = (l>>4)*8..+7
//                               C lane l -> col l&15, row = (l>>4)*4 + reg   [m89]

__global__ __launch_bounds__(256) void gemm1_mfma(
        const ushort* __restrict__ xb, const ushort* __restrict__ w1t,   // w1t: [256][128]
        const float* __restrict__ asrc, const float* __restrict__ adst,  // 256 each
        ushort* __restrict__ hb, float* __restrict__ os, float* __restrict__ od, int M) {
    const int lane = threadIdx.x & 63;
    const int c15 = lane & 15, rgrp = lane >> 4;
    const int row0 = blockIdx.x * 64 + (threadIdx.x >> 6) * 16;

    bf16x8 a[4];
#pragma unroll
    for (int ks = 0; ks < 4; ++ks)
        a[ks] = *(const bf16x8*)(xb + (size_t)(row0 + c15) * 128 + ks * 32 + rgrp * 8);

    f32x4 acc[16];
#pragma unroll
    for (int ct = 0; ct < 16; ++ct) acc[ct] = (f32x4){0.f, 0.f, 0.f, 0.f};

#pragma unroll
    for (int ct = 0; ct < 16; ++ct) {
        const ushort* bp = w1t + (size_t)(ct * 16 + c15) * 128 + rgrp * 8;
#pragma unroll
        for (int ks = 0; ks < 4; ++ks) {
            bf16x8 b = *(const bf16x8*)(bp + ks * 32);
            acc[ct] = __builtin_amdgcn_mfma_f32_16x16x32_bf16(a[ks], b, acc[ct], 0, 0, 0);
        }
    }

    // h store (bf16)
#pragma unroll
    for (int ct = 0; ct < 16; ++ct) {
        const int col = ct * 16 + c15;
#pragma unroll
        for (int r = 0; r < 4; ++r) {
            const int row = row0 + rgrp * 4 + r;
            if (row < M) hb[(size_t)row * 256 + col] = f2bf(acc[ct][r]);
        }
    }

    // attn dots: head hd <- col-tiles 4hd..4hd+3; reduce over the 16 col lanes
#pragma unroll
    for (int hd = 0; hd < 4; ++hd) {
        float sv[4] = {0.f, 0.f, 0.f, 0.f}, dv[4] = {0.f, 0.f, 0.f, 0.f};
#pragma unroll
        for (int j = 0; j < 4; ++j) {
            const int ct = hd * 4 + j;
            const float ws = asrc[ct * 16 + c15], wd = adst[ct * 16 + c15];
#pragma unroll
            for (int r = 0; r < 4; ++r) { sv[r] += acc[ct][r] * ws; dv[r] += acc[ct][r] * wd; }
        }
#pragma unroll
        for (int r = 0; r < 4; ++r) {
#pragma unroll
            for (int m = 1; m < 16; m <<= 1) {
                sv[r] += __shfl_xor(sv[r], m); dv[r] += __shfl_xor(dv[r], m);
            }
        }
        if (c15 == 0) {
#pragma unroll
            for (int r = 0; r < 4; ++r) {
                const int row = row0 + rgrp * 4 + r;
                if (row < M) { os[row * 4 + hd] = sv[r]; od[row * 4 + hd] = dv[r]; }
            }
        }
    }
}

// ---------------- MFMA GEMM2: h2[M,64] = aggb[M,256] @ W2, + attn dots ----------------

__global__ __launch_bounds__(256) void gemm2_mfma(
        const ushort* __restrict__ ab, const ushort* __restrict__ w2t,   // w2t: [64][256]
        const float* __restrict__ asrc, const float* __restrict__ adst,  // 64 each
        ushort* __restrict__ hb, float* __restrict__ os, float* __restrict__ od, int M) {
    const int lane = threadIdx.x & 63;
    const int c15 = lane & 15, rgrp = lane >> 4;
    const int row0 = blockIdx.x * 64 + (threadIdx.x >> 6) * 16;

    bf16x8 a[8];
#pragma unroll
    for (int ks = 0; ks < 8; ++ks)
        a[ks] = *(const bf16x8*)(ab + (size_t)(row0 + c15) * 256 + ks * 32 + rgrp * 8);

    f32x4 acc[4];
#pragma unroll
    for (int ct = 0; ct < 4; ++ct) acc[ct] = (f32x4){0.f, 0.f, 0.f, 0.f};

#pragma unroll
    for (int ct = 0; ct < 4; ++ct) {
        const ushort* bp = w2t + (size_t)(ct * 16 + c15) * 256 + rgrp * 8;
#pragma unroll
        for (int ks = 0; ks < 8; ++ks) {
            bf16x8 b = *(const bf16x8*)(bp + ks * 32);
            acc[ct] = __builtin_amdgcn_mfma_f32_16x16x32_bf16(a[ks], b, acc[ct], 0, 0, 0);
        }
    }

#pragma unroll
    for (int ct = 0; ct < 4; ++ct) {
        const int col = ct * 16 + c15;
#pragma unroll
        for (int r = 0; r < 4; ++r) {
            const int row = row0 + rgrp * 4 + r;
            if (row < M) hb[(size_t)row * 64 + col] = f2bf(acc[ct][r]);
        }
    }

    float sv[4] = {0.f, 0.f, 0.f, 0.f}, dv[4] = {0.f, 0.f, 0.f, 0.f};
#pragma unroll
    for (int ct = 0; ct < 4; ++ct) {
        const float ws = asrc[ct * 16 + c15], wd = adst[ct * 16 + c15];
#pragma unroll
        for (int r = 0; r < 4; ++r) { sv[r] += acc[ct][r] * ws; dv[r] += acc[ct][r] * wd; }
    }
#pragma unroll
    for (int r = 0; r < 4; ++r) {
#pragma unroll
        for (int m = 1; m < 16; m <<= 1) {
            sv[r] += __shfl_xor(sv[r], m); dv[r] += __shfl_xor(dv[r], m);
        }
    }
    if (c15 == 0) {
#pragma unroll
        for (int r = 0; r < 4; ++r) {
            const int row = row0 + rgrp * 4 + r;
            if (row < M) { os[row] = sv[r]; od[row] = dv[r]; }
        }
    }
}

// ---------------- CSR build: rank -> scan -> place ----------------

__global__ void rank_k(const int* __restrict__ ei, int E,
                       int* __restrict__ cnt, int* __restrict__ rnk) {
    int e = blockIdx.x * blockDim.x + threadIdx.x;
    if (e < E) rnk[e] = atomicAdd(&cnt[ei[E + e]], 1);
}

__global__ void scan1_k(const int* __restrict__ cnt, int* __restrict__ off,
                        int* __restrict__ bsum, int N) {
    __shared__ int tmp[256];
    const int i = blockIdx.x * 256 + threadIdx.x;
    int v = (i < N) ? cnt[i] : 0;
    tmp[threadIdx.x] = v;
    __syncthreads();
#pragma unroll
    for (int d = 1; d < 256; d <<= 1) {
        int t = (threadIdx.x >= d) ? tmp[threadIdx.x - d] : 0;
        __syncthreads();
        tmp[threadIdx.x] += t;
        __syncthreads();
    }
    if (i < N) off[i] = tmp[threadIdx.x] - v;
    if (threadIdx.x == 255) bsum[blockIdx.x] = tmp[255];
}

__global__ void scan23_k(int* __restrict__ off, const int* __restrict__ bsum, int N) {
    const int b = blockIdx.x;
    int pre = 0;
    for (int i = (threadIdx.x & 63); i < b; i += 64) pre += bsum[i];
#pragma unroll
    for (int m = 1; m < 64; m <<= 1) pre += __shfl_xor(pre, m);
    int i = b * 256 + threadIdx.x;
    if (i < N) off[i] += pre;
}

__global__ void place_k(const int* __restrict__ ei, int E, const int* __restrict__ off,
                        const int* __restrict__ rnk, int* __restrict__ csr) {
    int e = blockIdx.x * blockDim.x + threadIdx.x;
    if (e >= E) return;
    csr[off[ei[E + e]] + rnk[e]] = ei[e];
}

// ---------------- pull aggregation (bf16 gathers) ----------------

// layer 1: one wave per node; writes agg as bf16 (GEMM2 A operand)
__global__ __launch_bounds__(256) void pull1_k(
        const int* __restrict__ off, const int* __restrict__ cnt,
        const int* __restrict__ csr, const ushort* __restrict__ hb,
        const float* __restrict__ as, const float* __restrict__ ad,
        const float* __restrict__ bias, ushort* __restrict__ aggb, int N) {
    const int n = blockIdx.x * 4 + (threadIdx.x >> 6);
    if (n >= N) return;
    const int lane = threadIdx.x & 63;
    const int hh = lane >> 4;
    const float adv = ad[n * 4 + hh];
    const int start = off[n];
    const int end = start + cnt[n];
    float4 acc = {0.f, 0.f, 0.f, 0.f};
    float den = 0.f;
    int s_next = (start < end) ? csr[start] : 0;
    for (int i = start; i < end; ++i) {
        const int s = s_next;
        if (i + 1 < end) s_next = csr[i + 1];
        const float p = __expf(LRELU(as[s * 4 + hh] + adv));
        const ushort4 hv = *(const ushort4*)(hb + (size_t)s * 256 + lane * 4);
        den += p;
        acc.x += p * bf2f(hv.x); acc.y += p * bf2f(hv.y);
        acc.z += p * bf2f(hv.z); acc.w += p * bf2f(hv.w);
    }
    {   // self-loop
        const float p = __expf(LRELU(as[n * 4 + hh] + adv));
        const ushort4 hv = *(const ushort4*)(hb + (size_t)n * 256 + lane * 4);
        den += p;
        acc.x += p * bf2f(hv.x); acc.y += p * bf2f(hv.y);
        acc.z += p * bf2f(hv.z); acc.w += p * bf2f(hv.w);
    }
    const float rden = 1.f / den;
    const float4 bv = *(const float4*)(bias + lane * 4);
    ushort4 o;
    o.x = f2bf(fmaxf(acc.x * rden + bv.x, 0.f));
    o.y = f2bf(fmaxf(acc.y * rden + bv.y, 0.f));
    o.z = f2bf(fmaxf(acc.z * rden + bv.z, 0.f));
    o.w = f2bf(fmaxf(acc.w * rden + bv.w, 0.f));
    *(ushort4*)(aggb + (size_t)n * 256 + lane * 4) = o;
}

// layer 2: one wave per node, 4 edges/iter; fused bias + L2 norm; writes d_out
__global__ __launch_bounds__(256) void pull2_k(
        const int* __restrict__ off, const int* __restrict__ cnt,
        const int* __restrict__ csr, const ushort* __restrict__ hb,
        const float* __restrict__ as, const float* __restrict__ ad,
        const float* __restrict__ bias, float* __restrict__ out, int N) {
    const int n = blockIdx.x * 4 + (threadIdx.x >> 6);
    if (n >= N) return;
    const int lane = threadIdx.x & 63;
    const int g = lane >> 4;
    const int q = lane & 15;
    const float adv = ad[n];
    const int start = off[n];
    const int end = start + cnt[n];
    float4 acc = {0.f, 0.f, 0.f, 0.f};
    float den = 0.f;
    for (int base = start; base < end; base += 4) {
        const int idx = base + g;
        const bool valid = idx < end;
        const int s = valid ? csr[idx] : n;
        float p = __expf(LRELU(as[s] + adv));
        if (!valid) p = 0.f;
        const ushort4 hv = *(const ushort4*)(hb + (size_t)s * 64 + q * 4);
        den += p;
        acc.x += p * bf2f(hv.x); acc.y += p * bf2f(hv.y);
        acc.z += p * bf2f(hv.z); acc.w += p * bf2f(hv.w);
    }
    if (g == 0) {
        const float p = __expf(LRELU(as[n] + adv));
        const ushort4 hv = *(const ushort4*)(hb + (size_t)n * 64 + q * 4);
        den += p;
        acc.x += p * bf2f(hv.x); acc.y += p * bf2f(hv.y);
        acc.z += p * bf2f(hv.z); acc.w += p * bf2f(hv.w);
    }
#pragma unroll
    for (int m = 16; m < 64; m <<= 1) {
        acc.x += __shfl_xor(acc.x, m); acc.y += __shfl_xor(acc.y, m);
        acc.z += __shfl_xor(acc.z, m); acc.w += __shfl_xor(acc.w, m);
        den   += __shfl_xor(den, m);
    }
    const float rden = 1.f / den;
    const float4 bv = *(const float4*)(bias + q * 4);
    float4 v;
    v.x = acc.x * rden + bv.x; v.y = acc.y * rden + bv.y;
    v.z = acc.z * rden + bv.z; v.w = acc.w * rden + bv.w;
    float ss = v.x * v.x + v.y * v.y + v.z * v.z + v.w * v.w;
#pragma unroll
    for (int m = 1; m < 16; m <<= 1) ss += __shfl_xor(ss, m);
    const float rn = 1.f / fmaxf(sqrtf(ss), 1e-12f);
    if (g == 0) {
        float4 o; o.x = v.x * rn; o.y = v.y * rn; o.z = v.z * rn; o.w = v.w * rn;
        *(float4*)(out + (size_t)n * 64 + q * 4) = o;
    }
}

// ---------------- launch ----------------

extern "C" void kernel_launch(void* const* d_in, const int* in_sizes, int n_in,
                              void* d_out, int out_size, void* d_ws, size_t ws_size,
                              hipStream_t stream) {
    const float* x   = (const float*)d_in[0];
    const int*   ei1 = (const int*)d_in[1];
    const int*   ei2 = (const int*)d_in[2];
    const float* W1  = (const float*)d_in[3];
    const float* as1 = (const float*)d_in[4];
    const float* ad1 = (const float*)d_in[5];
    const float* b1  = (const float*)d_in[6];
    const float* W2  = (const float*)d_in[7];
    const float* as2 = (const float*)d_in[8];
    const float* ad2 = (const float*)d_in[9];
    const float* b2  = (const float*)d_in[10];

    const int N  = in_sizes[0] / 128;
    const int E1 = in_sizes[1] / 2;
    const int E2 = in_sizes[2] / 2;
    const int Emax = E1 > E2 ? E1 : E2;

    // ws layout (~79 MB)
    ushort* xb    = (ushort*)d_ws;                      // N*128 bf16
    ushort* h1b   = xb + (size_t)N * 128;               // N*256 bf16
    ushort* agg1b = h1b + (size_t)N * 256;              // N*256 bf16
    ushort* h2b   = agg1b + (size_t)N * 256;            // N*64  bf16
    ushort* w1t   = h2b + (size_t)N * 64;               // 256*128
    ushort* w2t   = w1t + 256 * 128;                    // 64*256
    int*    csr   = (int*)(w2t + 64 * 256);             // Emax
    int*    rnk   = csr + Emax;                         // Emax
    int*    cnt   = rnk + Emax;                         // N
    int*    off   = cnt + N;                            // N
    int*    bsum  = off + N;                            // 256
    float*  s1    = (float*)(bsum + 256);               // N*4
    float*  d1v   = s1 + (size_t)N * 4;                 // N*4
    float*  s2    = d1v + (size_t)N * 4;                // N
    float*  d2v   = s2 + N;                             // N
    float*  out   = (float*)d_out;

    const int nb = (N + 255) / 256;
    const int gblk = (N + 63) / 64;

    // prep casts
    cast4_k<<<((N * 128 / 4) + 255) / 256, 256, 0, stream>>>(x, xb, N * 128 / 4);
    tcast_k<<<(128 * 256 + 255) / 256, 256, 0, stream>>>(W1, w1t, 128, 256);
    tcast_k<<<(256 * 64 + 255) / 256, 256, 0, stream>>>(W2, w2t, 256, 64);

    // ---- layer 1 ----
    gemm1_mfma<<<gblk, 256, 0, stream>>>(xb, w1t, as1, ad1, h1b, s1, d1v, N);

    hipMemsetAsync(cnt, 0, (size_t)N * sizeof(int), stream);
    rank_k<<<(E1 + 255) / 256, 256, 0, stream>>>(ei1, E1, cnt, rnk);
    scan1_k<<<nb, 256, 0, stream>>>(cnt, off, bsum, N);
    scan23_k<<<nb, 256, 0, stream>>>(off, bsum, N);
    place_k<<<(E1 + 255) / 256, 256, 0, stream>>>(ei1, E1, off, rnk, csr);

    pull1_k<<<(N + 3) / 4, 256, 0, stream>>>(off, cnt, csr, h1b, s1, d1v, b1, agg1b, N);

    // ---- layer 2 ----
    gemm2_mfma<<<gblk, 256, 0, stream>>>(agg1b, w2t, as2, ad2, h2b, s2, d2v, N);

    hipMemsetAsync(cnt, 0, (size_t)N * sizeof(int), stream);
    rank_k<<<(E2 + 255) / 256, 256, 0, stream>>>(ei2, E2, cnt, rnk);
    scan1_k<<<nb, 256, 0, stream>>>(cnt, off, bsum, N);
    scan23_k<<<nb, 256, 0, stream>>>(off, bsum, N);
    place_k<<<(E2 + 255) / 256, 256, 0, stream>>>(ei2, E2, off, rnk, csr);

    pull2_k<<<(N + 3) / 4, 256, 0, stream>>>(off, cnt, csr, h2b, s2, d2v, b2, out, N);
}